// Round 13
// baseline (106.644 us; speedup 1.0000x reference)
//
#include <hip/hip_runtime.h>
#include <hip/hip_bf16.h>

#define NN 8192
#define INC 256
#define OUTC 512
#define NE 262144
#define MAXD 128
#define JC 8
#define JLEN 64  // OUTC / JC

typedef __hip_bfloat16 bf16;
typedef short bf16x8 __attribute__((ext_vector_type(8)));
typedef float f32x16 __attribute__((ext_vector_type(16)));

__device__ inline unsigned short f2bu(float f) {
  __hip_bfloat16 b = __float2bfloat16(f);
  return *reinterpret_cast<unsigned short*>(&b);
}
__device__ inline float blo(unsigned int x) { return __uint_as_float(x << 16); }
__device__ inline float bhi(unsigned int x) { return __uint_as_float(x & 0xffff0000u); }
__device__ inline float b2f(unsigned short s) { return __uint_as_float(((unsigned int)s) << 16); }

// P0: blocks 0..255 = x col-partials + bf16 cast + deg zero;
// blocks 256..1279 = Wc j-chunk partials (+ u,v partials on o-quad 0).
__global__ __launch_bounds__(256) void k_p0(const float* __restrict__ x,
                                            const float* __restrict__ W,
                                            const float* __restrict__ att_w,
                                            const float* __restrict__ lin_w,
                                            float* __restrict__ xpartT,
                                            unsigned short* __restrict__ xb,
                                            int* __restrict__ deg,
                                            float* __restrict__ part,
                                            float* __restrict__ uvpart) {
  int b = blockIdx.x, t = threadIdx.x;
  if (b < 256) {
    int gid = b * 256 + t;
    if (gid < NN) deg[gid] = 0;
    float acc = 0.f;
    int r0 = b * (NN / 256);
    for (int r = r0; r < r0 + NN / 256; ++r) {
      float xv = x[r * INC + t];
      acc += xv;
      xb[r * INC + t] = f2bu(xv);
    }
    xpartT[t * 256 + b] = acc;
    return;
  }
  int bid2 = b - 256;      // 0..1023
  int q = bid2 >> 3;       // o-quad 0..127
  int jc = bid2 & 7;
  int j0 = jc * JLEN;
  int o0 = q * 4;
  float a0 = 0.f, a1 = 0.f, a2 = 0.f, a3 = 0.f, su = 0.f, sv = 0.f;
  const float* lw0 = lin_w + (size_t)(o0 + 0) * OUTC + j0;
  const float* lw1 = lin_w + (size_t)(o0 + 1) * OUTC + j0;
  const float* lw2 = lin_w + (size_t)(o0 + 2) * OUTC + j0;
  const float* lw3 = lin_w + (size_t)(o0 + 3) * OUTC + j0;
#pragma unroll 8
  for (int jj = 0; jj < JLEN; ++jj) {
    float wv = W[(j0 + jj) * INC + t];
    a0 = fmaf(lw0[jj], wv, a0);
    a1 = fmaf(lw1[jj], wv, a1);
    a2 = fmaf(lw2[jj], wv, a2);
    a3 = fmaf(lw3[jj], wv, a3);
    if (q == 0) { su = fmaf(att_w[j0 + jj], wv, su); sv += wv; }
  }
  float* pb = part + ((size_t)jc * OUTC + o0) * INC + t;
  pb[0] = a0;
  pb[INC] = a1;
  pb[2 * INC] = a2;
  pb[3 * INC] = a3;
  if (q == 0) {
    uvpart[(jc * 2 + 0) * INC + t] = su;
    uvpart[(jc * 2 + 1) * INC + t] = sv;
  }
}

// P1 (385 blocks):
//  blocks 0..255: xsum reduce + 4 edges/thread atomicAdd(deg)->slot scatter
//  blocks 256..383: Wc reduce -> Wcb bf16
//  block 384: u,v
__global__ __launch_bounds__(256) void k_p1(const float* __restrict__ xpartT,
                                            float* __restrict__ xsum,
                                            const int* __restrict__ erow,
                                            const int* __restrict__ ecol,
                                            int* __restrict__ deg,
                                            int* __restrict__ colbuf2,
                                            const float* __restrict__ part,
                                            const float* __restrict__ uvpart,
                                            unsigned short* __restrict__ Wcb,
                                            float* __restrict__ u,
                                            float* __restrict__ v) {
  __shared__ float sred[4];
  int b = blockIdx.x, t = threadIdx.x;
  int l = t & 63, w = t >> 6;
  if (b < 256) {
    float r = xpartT[b * 256 + t];
#pragma unroll
    for (int off = 32; off > 0; off >>= 1) r += __shfl_xor(r, off);
    if (l == 0) sred[w] = r;
    int e0 = (b * 256 + t) * 4;
    int4 ev = *(const int4*)(erow + e0);
    int4 ec = *(const int4*)(ecol + e0);
    int s0 = atomicAdd(&deg[ev.x], 1);
    if (s0 < MAXD) colbuf2[ev.x * MAXD + s0] = ec.x;
    int s1 = atomicAdd(&deg[ev.y], 1);
    if (s1 < MAXD) colbuf2[ev.y * MAXD + s1] = ec.y;
    int s2 = atomicAdd(&deg[ev.z], 1);
    if (s2 < MAXD) colbuf2[ev.z * MAXD + s2] = ec.z;
    int s3 = atomicAdd(&deg[ev.w], 1);
    if (s3 < MAXD) colbuf2[ev.w * MAXD + s3] = ec.w;
    __syncthreads();
    if (t == 0) xsum[b] = sred[0] + sred[1] + sred[2] + sred[3];
  } else if (b < 384) {
    int o0 = (b - 256) * 4;
#pragma unroll
    for (int oo = 0; oo < 4; ++oo) {
      float s = 0.f;
#pragma unroll
      for (int jc = 0; jc < JC; ++jc)
        s += part[((size_t)jc * OUTC + o0 + oo) * INC + t];
      Wcb[(size_t)(o0 + oo) * INC + t] = f2bu(s);
    }
  } else {
    float su = 0.f, sv = 0.f;
#pragma unroll
    for (int jc = 0; jc < JC; ++jc) {
      su += uvpart[(jc * 2 + 0) * INC + t];
      sv += uvpart[(jc * 2 + 1) * INC + t];
    }
    u[t] = su;
    v[t] = sv;
  }
}

// blocks 0..1023: g = x @ Wc.T (MFMA 32x32x16, 64x64 tile, 2x2 waves)
// blocks 1024..1055: gsum[o] = Wcb[o,:].xsum
// blocks 1056..1087: alpha[i] = leaky_relu((x_i.u)*(x_i.v))  (hidden under GEMM)
__global__ __launch_bounds__(256) void k_gemm3(const unsigned short* __restrict__ xb,
                                               const unsigned short* __restrict__ wb,
                                               unsigned short* __restrict__ g,
                                               const float* __restrict__ xsum,
                                               float* __restrict__ gsum,
                                               const float* __restrict__ x,
                                               const float* __restrict__ u,
                                               const float* __restrict__ v,
                                               float* __restrict__ alpha) {
  int bk = blockIdx.x, t = threadIdx.x;
  int w = t >> 6, l = t & 63;
  if (bk >= 1056) {
    // alpha: 32 blocks x 4 waves; each wave 64 rows
    int base = (bk - 1056) * 256 + w * 64;
    float u0 = u[l], u1 = u[l + 64], u2 = u[l + 128], u3 = u[l + 192];
    float v0 = v[l], v1 = v[l + 64], v2 = v[l + 128], v3 = v[l + 192];
    for (int rr = 0; rr < 64; ++rr) {
      int i = base + rr;
      const float* xr = x + (size_t)i * INC;
      float x0 = xr[l], x1 = xr[l + 64], x2 = xr[l + 128], x3 = xr[l + 192];
      float su = x0 * u0 + x1 * u1 + x2 * u2 + x3 * u3;
      float sv = x0 * v0 + x1 * v1 + x2 * v2 + x3 * v3;
#pragma unroll
      for (int off = 32; off > 0; off >>= 1) {
        su += __shfl_xor(su, off);
        sv += __shfl_xor(sv, off);
      }
      if (l == 0) {
        float a = su * sv;
        alpha[i] = a > 0.f ? a : 0.2f * a;
      }
    }
    return;
  }
  if (bk >= 1024) {
    __shared__ float sred[4];
    int o0 = (bk - 1024) * 16;
    float xk = xsum[t];
    for (int oo = 0; oo < 16; ++oo) {
      float r = b2f(wb[(size_t)(o0 + oo) * INC + t]) * xk;
#pragma unroll
      for (int off = 32; off > 0; off >>= 1) r += __shfl_xor(r, off);
      if (l == 0) sred[w] = r;
      __syncthreads();
      if (t == 0) gsum[o0 + oo] = sred[0] + sred[1] + sred[2] + sred[3];
      __syncthreads();
    }
    return;
  }
  int bx = bk & 7, by = bk >> 3;
  int wm = w >> 1, wn = w & 1;
  int r0 = by * 64 + wm * 32;
  int c0 = bx * 64 + wn * 32;
  int lr = l & 31;
  int lk = (l >> 5) * 8;
  const unsigned short* pa = xb + (size_t)(r0 + lr) * INC + lk;
  const unsigned short* pb = wb + (size_t)(c0 + lr) * INC + lk;
  f32x16 acc = {};
#pragma unroll
  for (int k0 = 0; k0 < INC; k0 += 16) {
    bf16x8 a = *(const bf16x8*)(pa + k0);
    bf16x8 b = *(const bf16x8*)(pb + k0);
    acc = __builtin_amdgcn_mfma_f32_32x32x16_bf16(a, b, acc, 0, 0, 0);
  }
  // C/D: col = lane&31, row = (reg&3) + 8*(reg>>2) + 4*(lane>>5)
  int col = c0 + lr;
  int rbase = r0 + 4 * (l >> 5);
#pragma unroll
  for (int reg = 0; reg < 16; ++reg) {
    int row = rbase + (reg & 3) + 8 * (reg >> 2);
    g[(size_t)row * OUTC + col] = f2bu(acc[reg]);
  }
}

// FUSED coeff+aggregate: one wave per row; alpha precomputed.
__global__ __launch_bounds__(256) void k_sagg(const float* __restrict__ alpha,
                                              const float* __restrict__ gsum,
                                              const unsigned short* __restrict__ g,
                                              const int* __restrict__ deg,
                                              const int* __restrict__ colbuf2,
                                              float* __restrict__ out) {
  __shared__ int scols[4][MAXD];
  __shared__ float scoef[4][MAXD];
  int w = threadIdx.x >> 6, l = threadIdx.x & 63;
  int i = blockIdx.x * 4 + w;

  float al = alpha[i];
  int d = deg[i];
  if (d > MAXD) d = MAXD;
  const int* crow = colbuf2 + (size_t)i * MAXD;
  if (l < d) scols[w][l] = crow[l];
  int l2 = l + 64;
  if (l2 < d) scols[w][l2] = crow[l2];
  __syncthreads();
  int c0s = -1, c1s = -2;
  if (l < d) c0s = scols[w][l];
  if (l2 < d) c1s = scols[w][l2];
  int m0 = 0, m1 = 0, f0 = 1, f1 = 1;
  for (int q = 0; q < d; ++q) {
    int cq = scols[w][q];
    if (cq == c0s) { m0++; if (q < l) f0 = 0; }
    if (cq == c1s) { m1++; if (q < l2) f1 = 0; }
  }
  int mm = m0 > m1 ? m0 : m1;
#pragma unroll
  for (int off = 32; off > 0; off >>= 1) {
    int b = __shfl_xor(mm, off);
    if (b > mm) mm = b;
  }
  float M = (al > 0.f) ? al * (float)mm : 0.f;
  float eMn = expf(-M);
  float se = 0.f;
  int nc = 0;
  float cf0 = 0.f, cf1 = 0.f;
  if (l < d && f0) {
    float e0 = expf(al * (float)m0 - M);
    se += e0; nc++; cf0 = e0 - eMn;
  }
  if (l2 < d && f1) {
    float e1 = expf(al * (float)m1 - M);
    se += e1; nc++; cf1 = e1 - eMn;
  }
#pragma unroll
  for (int off = 32; off > 0; off >>= 1) {
    se += __shfl_xor(se, off);
    nc += __shfl_xor(nc, off);
  }
  float Z = (float)(NN - nc) * eMn + se;
  float invZ = 1.0f / Z;
  if (l < d) scoef[w][l] = cf0 * invZ;
  if (l2 < d) scoef[w][l2] = cf1 * invZ;
  float rs = eMn * invZ;

  // Phase B: gather. lane owns channels [8l, 8l+8); 2-way unrolled.
  int c0 = l * 8;
  float acc[8];
  float4 gs0 = *(const float4*)(gsum + c0);
  float4 gs1 = *(const float4*)(gsum + c0 + 4);
  acc[0] = rs * gs0.x; acc[1] = rs * gs0.y; acc[2] = rs * gs0.z; acc[3] = rs * gs0.w;
  acc[4] = rs * gs1.x; acc[5] = rs * gs1.y; acc[6] = rs * gs1.z; acc[7] = rs * gs1.w;
  int k = 0;
  for (; k + 2 <= d; k += 2) {
    int ca = scols[w][k], cb = scols[w][k + 1];
    float fa = scoef[w][k], fb = scoef[w][k + 1];
    uint4 pva = *(const uint4*)(g + (size_t)ca * OUTC + c0);
    uint4 pvb = *(const uint4*)(g + (size_t)cb * OUTC + c0);
    acc[0] = fmaf(fa, blo(pva.x), fmaf(fb, blo(pvb.x), acc[0]));
    acc[1] = fmaf(fa, bhi(pva.x), fmaf(fb, bhi(pvb.x), acc[1]));
    acc[2] = fmaf(fa, blo(pva.y), fmaf(fb, blo(pvb.y), acc[2]));
    acc[3] = fmaf(fa, bhi(pva.y), fmaf(fb, bhi(pvb.y), acc[3]));
    acc[4] = fmaf(fa, blo(pva.z), fmaf(fb, blo(pvb.z), acc[4]));
    acc[5] = fmaf(fa, bhi(pva.z), fmaf(fb, bhi(pvb.z), acc[5]));
    acc[6] = fmaf(fa, blo(pva.w), fmaf(fb, blo(pvb.w), acc[6]));
    acc[7] = fmaf(fa, bhi(pva.w), fmaf(fb, bhi(pvb.w), acc[7]));
  }
  if (k < d) {
    int ca = scols[w][k];
    float fa = scoef[w][k];
    uint4 pva = *(const uint4*)(g + (size_t)ca * OUTC + c0);
    acc[0] = fmaf(fa, blo(pva.x), acc[0]);
    acc[1] = fmaf(fa, bhi(pva.x), acc[1]);
    acc[2] = fmaf(fa, blo(pva.y), acc[2]);
    acc[3] = fmaf(fa, bhi(pva.y), acc[3]);
    acc[4] = fmaf(fa, blo(pva.z), acc[4]);
    acc[5] = fmaf(fa, bhi(pva.z), acc[5]);
    acc[6] = fmaf(fa, blo(pva.w), acc[6]);
    acc[7] = fmaf(fa, bhi(pva.w), acc[7]);
  }
  float4 o0, o1;
  o0.x = acc[0] > 0.f ? acc[0] : expm1f(acc[0]);
  o0.y = acc[1] > 0.f ? acc[1] : expm1f(acc[1]);
  o0.z = acc[2] > 0.f ? acc[2] : expm1f(acc[2]);
  o0.w = acc[3] > 0.f ? acc[3] : expm1f(acc[3]);
  o1.x = acc[4] > 0.f ? acc[4] : expm1f(acc[4]);
  o1.y = acc[5] > 0.f ? acc[5] : expm1f(acc[5]);
  o1.z = acc[6] > 0.f ? acc[6] : expm1f(acc[6]);
  o1.w = acc[7] > 0.f ? acc[7] : expm1f(acc[7]);
  float* po = out + (size_t)i * OUTC + c0;
  *(float4*)po = o0;
  *(float4*)(po + 4) = o1;
}

extern "C" void kernel_launch(void* const* d_in, const int* in_sizes, int n_in,
                              void* d_out, int out_size, void* d_ws, size_t ws_size,
                              hipStream_t stream) {
  const float* x = (const float*)d_in[0];
  const int* ei = (const int*)d_in[1];
  const float* W = (const float*)d_in[2];
  const float* att_w = (const float*)d_in[3];
  const float* lin_w = (const float*)d_in[4];
  float* out = (float*)d_out;
  const int* erow = ei;
  const int* ecol = ei + NE;

  char* ws = (char*)d_ws;
  size_t off = 0;
  auto alloc = [&](size_t bytes) {
    void* p = ws + off;
    off = (off + bytes + 255) & ~(size_t)255;
    return p;
  };
  float* u = (float*)alloc(INC * 4);
  float* v = (float*)alloc(INC * 4);
  float* xsum = (float*)alloc(INC * 4);
  float* xpartT = (float*)alloc(INC * 256 * 4);
  float* gsum = (float*)alloc(OUTC * 4);
  float* alpha = (float*)alloc(NN * 4);
  float* part = (float*)alloc((size_t)JC * OUTC * INC * 4);
  float* uvpart = (float*)alloc(JC * 2 * INC * 4);
  unsigned short* Wcb = (unsigned short*)alloc((size_t)OUTC * INC * 2);
  unsigned short* xb = (unsigned short*)alloc((size_t)NN * INC * 2);
  unsigned short* g = (unsigned short*)alloc((size_t)NN * OUTC * 2);
  int* deg = (int*)alloc(NN * 4);
  int* colbuf2 = (int*)alloc((size_t)NN * MAXD * 4);
  (void)ws_size; (void)in_sizes; (void)n_in; (void)out_size;

  k_p0<<<256 + 1024, 256, 0, stream>>>(x, W, att_w, lin_w, xpartT, xb, deg, part, uvpart);
  k_p1<<<385, 256, 0, stream>>>(xpartT, xsum, erow, ecol, deg, colbuf2, part, uvpart, Wcb, u, v);
  k_gemm3<<<1024 + 32 + 32, 256, 0, stream>>>(xb, Wcb, g, xsum, gsum, x, u, v, alpha);
  k_sagg<<<NN / 4, 256, 0, stream>>>(alpha, gsum, g, deg, colbuf2, out);
}

// Round 14
// 85.058 us; speedup vs baseline: 1.2538x; 1.2538x over previous
//
#include <hip/hip_runtime.h>
#include <hip/hip_bf16.h>

#define NN 8192
#define INC 256
#define OUTC 512
#define NE 262144
#define MAXD 128
#define JC 8
#define JLEN 64  // OUTC / JC

typedef __hip_bfloat16 bf16;
typedef short bf16x8 __attribute__((ext_vector_type(8)));
typedef float f32x16 __attribute__((ext_vector_type(16)));

__device__ inline unsigned short f2bu(float f) {
  __hip_bfloat16 b = __float2bfloat16(f);
  return *reinterpret_cast<unsigned short*>(&b);
}
__device__ inline float blo(unsigned int x) { return __uint_as_float(x << 16); }
__device__ inline float bhi(unsigned int x) { return __uint_as_float(x & 0xffff0000u); }
__device__ inline float b2f(unsigned short s) { return __uint_as_float(((unsigned int)s) << 16); }

// P0: blocks 0..255 = x col-partials + bf16 cast + deg zero;
// blocks 256..1279 = Wc j-chunk partials (+ u,v partials on o-quad 0).
__global__ __launch_bounds__(256) void k_p0(const float* __restrict__ x,
                                            const float* __restrict__ W,
                                            const float* __restrict__ att_w,
                                            const float* __restrict__ lin_w,
                                            float* __restrict__ xpartT,
                                            unsigned short* __restrict__ xb,
                                            int* __restrict__ deg,
                                            float* __restrict__ part,
                                            float* __restrict__ uvpart) {
  int b = blockIdx.x, t = threadIdx.x;
  if (b < 256) {
    int gid = b * 256 + t;
    if (gid < NN) deg[gid] = 0;
    float acc = 0.f;
    int r0 = b * (NN / 256);
    for (int r = r0; r < r0 + NN / 256; ++r) {
      float xv = x[r * INC + t];
      acc += xv;
      xb[r * INC + t] = f2bu(xv);
    }
    xpartT[t * 256 + b] = acc;
    return;
  }
  int bid2 = b - 256;      // 0..1023
  int q = bid2 >> 3;       // o-quad 0..127
  int jc = bid2 & 7;
  int j0 = jc * JLEN;
  int o0 = q * 4;
  float a0 = 0.f, a1 = 0.f, a2 = 0.f, a3 = 0.f, su = 0.f, sv = 0.f;
  const float* lw0 = lin_w + (size_t)(o0 + 0) * OUTC + j0;
  const float* lw1 = lin_w + (size_t)(o0 + 1) * OUTC + j0;
  const float* lw2 = lin_w + (size_t)(o0 + 2) * OUTC + j0;
  const float* lw3 = lin_w + (size_t)(o0 + 3) * OUTC + j0;
#pragma unroll 8
  for (int jj = 0; jj < JLEN; ++jj) {
    float wv = W[(j0 + jj) * INC + t];
    a0 = fmaf(lw0[jj], wv, a0);
    a1 = fmaf(lw1[jj], wv, a1);
    a2 = fmaf(lw2[jj], wv, a2);
    a3 = fmaf(lw3[jj], wv, a3);
    if (q == 0) { su = fmaf(att_w[j0 + jj], wv, su); sv += wv; }
  }
  float* pb = part + ((size_t)jc * OUTC + o0) * INC + t;
  pb[0] = a0;
  pb[INC] = a1;
  pb[2 * INC] = a2;
  pb[3 * INC] = a3;
  if (q == 0) {
    uvpart[(jc * 2 + 0) * INC + t] = su;
    uvpart[(jc * 2 + 1) * INC + t] = sv;
  }
}

// P1 (385 blocks):
//  blocks 0..255: xsum reduce + 4 edges/thread atomicAdd(deg)->slot scatter
//  blocks 256..383: Wc reduce -> Wcb bf16
//  block 384: u,v
__global__ __launch_bounds__(256) void k_p1(const float* __restrict__ xpartT,
                                            float* __restrict__ xsum,
                                            const int* __restrict__ erow,
                                            const int* __restrict__ ecol,
                                            int* __restrict__ deg,
                                            int* __restrict__ colbuf2,
                                            const float* __restrict__ part,
                                            const float* __restrict__ uvpart,
                                            unsigned short* __restrict__ Wcb,
                                            float* __restrict__ u,
                                            float* __restrict__ v) {
  __shared__ float sred[4];
  int b = blockIdx.x, t = threadIdx.x;
  int l = t & 63, w = t >> 6;
  if (b < 256) {
    float r = xpartT[b * 256 + t];
#pragma unroll
    for (int off = 32; off > 0; off >>= 1) r += __shfl_xor(r, off);
    if (l == 0) sred[w] = r;
    int e0 = (b * 256 + t) * 4;
    int4 ev = *(const int4*)(erow + e0);
    int4 ec = *(const int4*)(ecol + e0);
    int s0 = atomicAdd(&deg[ev.x], 1);
    if (s0 < MAXD) colbuf2[ev.x * MAXD + s0] = ec.x;
    int s1 = atomicAdd(&deg[ev.y], 1);
    if (s1 < MAXD) colbuf2[ev.y * MAXD + s1] = ec.y;
    int s2 = atomicAdd(&deg[ev.z], 1);
    if (s2 < MAXD) colbuf2[ev.z * MAXD + s2] = ec.z;
    int s3 = atomicAdd(&deg[ev.w], 1);
    if (s3 < MAXD) colbuf2[ev.w * MAXD + s3] = ec.w;
    __syncthreads();
    if (t == 0) xsum[b] = sred[0] + sred[1] + sred[2] + sred[3];
  } else if (b < 384) {
    int o0 = (b - 256) * 4;
#pragma unroll
    for (int oo = 0; oo < 4; ++oo) {
      float s = 0.f;
#pragma unroll
      for (int jc = 0; jc < JC; ++jc)
        s += part[((size_t)jc * OUTC + o0 + oo) * INC + t];
      Wcb[(size_t)(o0 + oo) * INC + t] = f2bu(s);
    }
  } else {
    float su = 0.f, sv = 0.f;
#pragma unroll
    for (int jc = 0; jc < JC; ++jc) {
      su += uvpart[(jc * 2 + 0) * INC + t];
      sv += uvpart[(jc * 2 + 1) * INC + t];
    }
    u[t] = su;
    v[t] = sv;
  }
}

// blocks 0..1023: g = x @ Wc.T (MFMA 32x32x16, 64x64 tile, 2x2 waves)
//   C-write staged through LDS -> coalesced 16B/lane stores.
// blocks 1024..1055: gsum[o] = Wcb[o,:].xsum
__global__ __launch_bounds__(256) void k_gemm3(const unsigned short* __restrict__ xb,
                                               const unsigned short* __restrict__ wb,
                                               unsigned short* __restrict__ g,
                                               const float* __restrict__ xsum,
                                               float* __restrict__ gsum) {
  int bk = blockIdx.x, t = threadIdx.x;
  int w = t >> 6, l = t & 63;
  if (bk >= 1024) {
    __shared__ float sred[4];
    int o0 = (bk - 1024) * 16;
    float xk = xsum[t];
    for (int oo = 0; oo < 16; ++oo) {
      float r = b2f(wb[(size_t)(o0 + oo) * INC + t]) * xk;
#pragma unroll
      for (int off = 32; off > 0; off >>= 1) r += __shfl_xor(r, off);
      if (l == 0) sred[w] = r;
      __syncthreads();
      if (t == 0) gsum[o0 + oo] = sred[0] + sred[1] + sred[2] + sred[3];
      __syncthreads();
    }
    return;
  }
  __shared__ unsigned short tile[64][72];  // pad 72: 144B row stride, 16B-aligned
  int bx = bk & 7, by = bk >> 3;
  int wm = w >> 1, wn = w & 1;
  int r0 = by * 64 + wm * 32;
  int c0 = bx * 64 + wn * 32;
  int lr = l & 31;
  int lk = (l >> 5) * 8;
  const unsigned short* pa = xb + (size_t)(r0 + lr) * INC + lk;
  const unsigned short* pb = wb + (size_t)(c0 + lr) * INC + lk;
  f32x16 acc = {};
#pragma unroll
  for (int k0 = 0; k0 < INC; k0 += 16) {
    bf16x8 a = *(const bf16x8*)(pa + k0);
    bf16x8 b = *(const bf16x8*)(pb + k0);
    acc = __builtin_amdgcn_mfma_f32_32x32x16_bf16(a, b, acc, 0, 0, 0);
  }
  // C/D: col = lane&31, row = (reg&3) + 8*(reg>>2) + 4*(lane>>5)  -> LDS tile
  int lcol = wn * 32 + lr;
  int lrb = wm * 32 + 4 * (l >> 5);
#pragma unroll
  for (int reg = 0; reg < 16; ++reg) {
    int lrow = lrb + (reg & 3) + 8 * (reg >> 2);
    tile[lrow][lcol] = f2bu(acc[reg]);
  }
  __syncthreads();
  // coalesced write-out: thread t -> rows (t>>3) and (t>>3)+32, 8 cols each
  int trow = t >> 3, tcol = (t & 7) * 8;
  size_t gbase = (size_t)(by * 64) * OUTC + bx * 64 + tcol;
  *(uint4*)(g + gbase + (size_t)trow * OUTC) = *(const uint4*)&tile[trow][tcol];
  *(uint4*)(g + gbase + (size_t)(trow + 32) * OUTC) = *(const uint4*)&tile[trow + 32][tcol];
}

// FUSED coeff+aggregate: one wave per row (alpha computed inline).
__global__ __launch_bounds__(256) void k_sagg(const float* __restrict__ x,
                                              const float* __restrict__ u,
                                              const float* __restrict__ v,
                                              const float* __restrict__ gsum,
                                              const unsigned short* __restrict__ g,
                                              const int* __restrict__ deg,
                                              const int* __restrict__ colbuf2,
                                              float* __restrict__ out) {
  __shared__ int scols[4][MAXD];
  __shared__ float scoef[4][MAXD];
  int w = threadIdx.x >> 6, l = threadIdx.x & 63;
  int i = blockIdx.x * 4 + w;

  // alpha_i = leaky_relu((x_i.u)*(x_i.v))
  float su = 0.f, sv = 0.f;
#pragma unroll
  for (int kk = 0; kk < 4; ++kk) {
    int k = l + kk * 64;
    float xv = x[(size_t)i * INC + k];
    su = fmaf(xv, u[k], su);
    sv = fmaf(xv, v[k], sv);
  }
#pragma unroll
  for (int off = 32; off > 0; off >>= 1) {
    su += __shfl_xor(su, off);
    sv += __shfl_xor(sv, off);
  }
  float a = su * sv;
  float al = a > 0.f ? a : 0.2f * a;

  int d = deg[i];
  if (d > MAXD) d = MAXD;
  const int* crow = colbuf2 + (size_t)i * MAXD;
  if (l < d) scols[w][l] = crow[l];
  int l2 = l + 64;
  if (l2 < d) scols[w][l2] = crow[l2];
  __syncthreads();
  int c0s = -1, c1s = -2;
  if (l < d) c0s = scols[w][l];
  if (l2 < d) c1s = scols[w][l2];
  int m0 = 0, m1 = 0, f0 = 1, f1 = 1;
  for (int q = 0; q < d; ++q) {
    int cq = scols[w][q];
    if (cq == c0s) { m0++; if (q < l) f0 = 0; }
    if (cq == c1s) { m1++; if (q < l2) f1 = 0; }
  }
  int mm = m0 > m1 ? m0 : m1;
#pragma unroll
  for (int off = 32; off > 0; off >>= 1) {
    int b = __shfl_xor(mm, off);
    if (b > mm) mm = b;
  }
  float M = (al > 0.f) ? al * (float)mm : 0.f;
  float eMn = expf(-M);
  float se = 0.f;
  int nc = 0;
  float cf0 = 0.f, cf1 = 0.f;
  if (l < d && f0) {
    float e0 = expf(al * (float)m0 - M);
    se += e0; nc++; cf0 = e0 - eMn;
  }
  if (l2 < d && f1) {
    float e1 = expf(al * (float)m1 - M);
    se += e1; nc++; cf1 = e1 - eMn;
  }
#pragma unroll
  for (int off = 32; off > 0; off >>= 1) {
    se += __shfl_xor(se, off);
    nc += __shfl_xor(nc, off);
  }
  float Z = (float)(NN - nc) * eMn + se;
  float invZ = 1.0f / Z;
  if (l < d) scoef[w][l] = cf0 * invZ;
  if (l2 < d) scoef[w][l2] = cf1 * invZ;
  float rs = eMn * invZ;

  // Phase B: gather. lane owns channels [8l, 8l+8); 2-way unrolled.
  int c0 = l * 8;
  float acc[8];
  float4 gs0 = *(const float4*)(gsum + c0);
  float4 gs1 = *(const float4*)(gsum + c0 + 4);
  acc[0] = rs * gs0.x; acc[1] = rs * gs0.y; acc[2] = rs * gs0.z; acc[3] = rs * gs0.w;
  acc[4] = rs * gs1.x; acc[5] = rs * gs1.y; acc[6] = rs * gs1.z; acc[7] = rs * gs1.w;
  int k = 0;
  for (; k + 2 <= d; k += 2) {
    int ca = scols[w][k], cb = scols[w][k + 1];
    float fa = scoef[w][k], fb = scoef[w][k + 1];
    uint4 pva = *(const uint4*)(g + (size_t)ca * OUTC + c0);
    uint4 pvb = *(const uint4*)(g + (size_t)cb * OUTC + c0);
    acc[0] = fmaf(fa, blo(pva.x), fmaf(fb, blo(pvb.x), acc[0]));
    acc[1] = fmaf(fa, bhi(pva.x), fmaf(fb, bhi(pvb.x), acc[1]));
    acc[2] = fmaf(fa, blo(pva.y), fmaf(fb, blo(pvb.y), acc[2]));
    acc[3] = fmaf(fa, bhi(pva.y), fmaf(fb, bhi(pvb.y), acc[3]));
    acc[4] = fmaf(fa, blo(pva.z), fmaf(fb, blo(pvb.z), acc[4]));
    acc[5] = fmaf(fa, bhi(pva.z), fmaf(fb, bhi(pvb.z), acc[5]));
    acc[6] = fmaf(fa, blo(pva.w), fmaf(fb, blo(pvb.w), acc[6]));
    acc[7] = fmaf(fa, bhi(pva.w), fmaf(fb, bhi(pvb.w), acc[7]));
  }
  if (k < d) {
    int ca = scols[w][k];
    float fa = scoef[w][k];
    uint4 pva = *(const uint4*)(g + (size_t)ca * OUTC + c0);
    acc[0] = fmaf(fa, blo(pva.x), acc[0]);
    acc[1] = fmaf(fa, bhi(pva.x), acc[1]);
    acc[2] = fmaf(fa, blo(pva.y), acc[2]);
    acc[3] = fmaf(fa, bhi(pva.y), acc[3]);
    acc[4] = fmaf(fa, blo(pva.z), acc[4]);
    acc[5] = fmaf(fa, bhi(pva.z), acc[5]);
    acc[6] = fmaf(fa, blo(pva.w), acc[6]);
    acc[7] = fmaf(fa, bhi(pva.w), acc[7]);
  }
  float4 o0, o1;
  o0.x = acc[0] > 0.f ? acc[0] : expm1f(acc[0]);
  o0.y = acc[1] > 0.f ? acc[1] : expm1f(acc[1]);
  o0.z = acc[2] > 0.f ? acc[2] : expm1f(acc[2]);
  o0.w = acc[3] > 0.f ? acc[3] : expm1f(acc[3]);
  o1.x = acc[4] > 0.f ? acc[4] : expm1f(acc[4]);
  o1.y = acc[5] > 0.f ? acc[5] : expm1f(acc[5]);
  o1.z = acc[6] > 0.f ? acc[6] : expm1f(acc[6]);
  o1.w = acc[7] > 0.f ? acc[7] : expm1f(acc[7]);
  float* po = out + (size_t)i * OUTC + c0;
  *(float4*)po = o0;
  *(float4*)(po + 4) = o1;
}

extern "C" void kernel_launch(void* const* d_in, const int* in_sizes, int n_in,
                              void* d_out, int out_size, void* d_ws, size_t ws_size,
                              hipStream_t stream) {
  const float* x = (const float*)d_in[0];
  const int* ei = (const int*)d_in[1];
  const float* W = (const float*)d_in[2];
  const float* att_w = (const float*)d_in[3];
  const float* lin_w = (const float*)d_in[4];
  float* out = (float*)d_out;
  const int* erow = ei;
  const int* ecol = ei + NE;

  char* ws = (char*)d_ws;
  size_t off = 0;
  auto alloc = [&](size_t bytes) {
    void* p = ws + off;
    off = (off + bytes + 255) & ~(size_t)255;
    return p;
  };
  float* u = (float*)alloc(INC * 4);
  float* v = (float*)alloc(INC * 4);
  float* xsum = (float*)alloc(INC * 4);
  float* xpartT = (float*)alloc(INC * 256 * 4);
  float* gsum = (float*)alloc(OUTC * 4);
  float* part = (float*)alloc((size_t)JC * OUTC * INC * 4);
  float* uvpart = (float*)alloc(JC * 2 * INC * 4);
  unsigned short* Wcb = (unsigned short*)alloc((size_t)OUTC * INC * 2);
  unsigned short* xb = (unsigned short*)alloc((size_t)NN * INC * 2);
  unsigned short* g = (unsigned short*)alloc((size_t)NN * OUTC * 2);
  int* deg = (int*)alloc(NN * 4);
  int* colbuf2 = (int*)alloc((size_t)NN * MAXD * 4);
  (void)ws_size; (void)in_sizes; (void)n_in; (void)out_size;

  k_p0<<<256 + 1024, 256, 0, stream>>>(x, W, att_w, lin_w, xpartT, xb, deg, part, uvpart);
  k_p1<<<385, 256, 0, stream>>>(xpartT, xsum, erow, ecol, deg, colbuf2, part, uvpart, Wcb, u, v);
  k_gemm3<<<1024 + 32, 256, 0, stream>>>(xb, Wcb, g, xsum, gsum);
  k_sagg<<<NN / 4, 256, 0, stream>>>(x, u, v, gsum, g, deg, colbuf2, out);
}

// Round 15
// 71.119 us; speedup vs baseline: 1.4995x; 1.1960x over previous
//
#include <hip/hip_runtime.h>
#include <hip/hip_bf16.h>

#define NN 8192
#define INC 256
#define OUTC 512
#define NE 262144
#define MAXD 128
#define JC 8
#define JLEN 64  // OUTC / JC

typedef __hip_bfloat16 bf16;
typedef short bf16x8 __attribute__((ext_vector_type(8)));
typedef float f32x16 __attribute__((ext_vector_type(16)));

__device__ inline unsigned short f2bu(float f) {
  __hip_bfloat16 b = __float2bfloat16(f);
  return *reinterpret_cast<unsigned short*>(&b);
}
__device__ inline float blo(unsigned int x) { return __uint_as_float(x << 16); }
__device__ inline float bhi(unsigned int x) { return __uint_as_float(x & 0xffff0000u); }
__device__ inline float b2f(unsigned short s) { return __uint_as_float(((unsigned int)s) << 16); }

// P0: blocks 0..255 = x col-partials + bf16 cast + deg zero;
// blocks 256..1279 = Wc j-chunk partials (+ u,v partials on o-quad 0).
__global__ __launch_bounds__(256) void k_p0(const float* __restrict__ x,
                                            const float* __restrict__ W,
                                            const float* __restrict__ att_w,
                                            const float* __restrict__ lin_w,
                                            float* __restrict__ xpartT,
                                            unsigned short* __restrict__ xb,
                                            int* __restrict__ deg,
                                            float* __restrict__ part,
                                            float* __restrict__ uvpart) {
  int b = blockIdx.x, t = threadIdx.x;
  if (b < 256) {
    int gid = b * 256 + t;
    if (gid < NN) deg[gid] = 0;
    float acc = 0.f;
    int r0 = b * (NN / 256);
    for (int r = r0; r < r0 + NN / 256; ++r) {
      float xv = x[r * INC + t];
      acc += xv;
      xb[r * INC + t] = f2bu(xv);
    }
    xpartT[t * 256 + b] = acc;
    return;
  }
  int bid2 = b - 256;      // 0..1023
  int q = bid2 >> 3;       // o-quad 0..127
  int jc = bid2 & 7;
  int j0 = jc * JLEN;
  int o0 = q * 4;
  float a0 = 0.f, a1 = 0.f, a2 = 0.f, a3 = 0.f, su = 0.f, sv = 0.f;
  const float* lw0 = lin_w + (size_t)(o0 + 0) * OUTC + j0;
  const float* lw1 = lin_w + (size_t)(o0 + 1) * OUTC + j0;
  const float* lw2 = lin_w + (size_t)(o0 + 2) * OUTC + j0;
  const float* lw3 = lin_w + (size_t)(o0 + 3) * OUTC + j0;
#pragma unroll 8
  for (int jj = 0; jj < JLEN; ++jj) {
    float wv = W[(j0 + jj) * INC + t];
    a0 = fmaf(lw0[jj], wv, a0);
    a1 = fmaf(lw1[jj], wv, a1);
    a2 = fmaf(lw2[jj], wv, a2);
    a3 = fmaf(lw3[jj], wv, a3);
    if (q == 0) { su = fmaf(att_w[j0 + jj], wv, su); sv += wv; }
  }
  float* pb = part + ((size_t)jc * OUTC + o0) * INC + t;
  pb[0] = a0;
  pb[INC] = a1;
  pb[2 * INC] = a2;
  pb[3 * INC] = a3;
  if (q == 0) {
    uvpart[(jc * 2 + 0) * INC + t] = su;
    uvpart[(jc * 2 + 1) * INC + t] = sv;
  }
}

// P1 (385 blocks):
//  blocks 0..255: xsum reduce + 4 edges/thread atomicAdd(deg)->slot scatter
//  blocks 256..383: Wc reduce -> Wcb bf16
//  block 384: u,v
__global__ __launch_bounds__(256) void k_p1(const float* __restrict__ xpartT,
                                            float* __restrict__ xsum,
                                            const int* __restrict__ erow,
                                            const int* __restrict__ ecol,
                                            int* __restrict__ deg,
                                            int* __restrict__ colbuf2,
                                            const float* __restrict__ part,
                                            const float* __restrict__ uvpart,
                                            unsigned short* __restrict__ Wcb,
                                            float* __restrict__ u,
                                            float* __restrict__ v) {
  __shared__ float sred[4];
  int b = blockIdx.x, t = threadIdx.x;
  int l = t & 63, w = t >> 6;
  if (b < 256) {
    float r = xpartT[b * 256 + t];
#pragma unroll
    for (int off = 32; off > 0; off >>= 1) r += __shfl_xor(r, off);
    if (l == 0) sred[w] = r;
    int e0 = (b * 256 + t) * 4;
    int4 ev = *(const int4*)(erow + e0);
    int4 ec = *(const int4*)(ecol + e0);
    int s0 = atomicAdd(&deg[ev.x], 1);
    if (s0 < MAXD) colbuf2[ev.x * MAXD + s0] = ec.x;
    int s1 = atomicAdd(&deg[ev.y], 1);
    if (s1 < MAXD) colbuf2[ev.y * MAXD + s1] = ec.y;
    int s2 = atomicAdd(&deg[ev.z], 1);
    if (s2 < MAXD) colbuf2[ev.z * MAXD + s2] = ec.z;
    int s3 = atomicAdd(&deg[ev.w], 1);
    if (s3 < MAXD) colbuf2[ev.w * MAXD + s3] = ec.w;
    __syncthreads();
    if (t == 0) xsum[b] = sred[0] + sred[1] + sred[2] + sred[3];
  } else if (b < 384) {
    int o0 = (b - 256) * 4;
#pragma unroll
    for (int oo = 0; oo < 4; ++oo) {
      float s = 0.f;
#pragma unroll
      for (int jc = 0; jc < JC; ++jc)
        s += part[((size_t)jc * OUTC + o0 + oo) * INC + t];
      Wcb[(size_t)(o0 + oo) * INC + t] = f2bu(s);
    }
  } else {
    float su = 0.f, sv = 0.f;
#pragma unroll
    for (int jc = 0; jc < JC; ++jc) {
      su += uvpart[(jc * 2 + 0) * INC + t];
      sv += uvpart[(jc * 2 + 1) * INC + t];
    }
    u[t] = su;
    v[t] = sv;
  }
}

// Coeff + gather-x aggregation: one wave per row.
// y[i,:] = sum_k cf_k * xb[col_k, :]  (bf16 out), rowscale[i] = e^{-M}/Z.
// Blocks 2048..2079: gsum[o] = Wcb[o,:].xsum
__global__ __launch_bounds__(256) void k_sagg2(const float* __restrict__ x,
                                               const float* __restrict__ u,
                                               const float* __restrict__ v,
                                               const unsigned short* __restrict__ xb,
                                               const int* __restrict__ deg,
                                               const int* __restrict__ colbuf2,
                                               const unsigned short* __restrict__ Wcb,
                                               const float* __restrict__ xsum,
                                               unsigned short* __restrict__ y,
                                               float* __restrict__ rowscale,
                                               float* __restrict__ gsum) {
  int bk = blockIdx.x, t = threadIdx.x;
  int w = t >> 6, l = t & 63;
  if (bk >= 2048) {
    __shared__ float sredg[4];
    int o0 = (bk - 2048) * 16;
    float xk = xsum[t];
    for (int oo = 0; oo < 16; ++oo) {
      float r = b2f(Wcb[(size_t)(o0 + oo) * INC + t]) * xk;
#pragma unroll
      for (int off = 32; off > 0; off >>= 1) r += __shfl_xor(r, off);
      if (l == 0) sredg[w] = r;
      __syncthreads();
      if (t == 0) gsum[o0 + oo] = sredg[0] + sredg[1] + sredg[2] + sredg[3];
      __syncthreads();
    }
    return;
  }
  __shared__ int scols[4][MAXD];
  __shared__ float scoef[4][MAXD];
  int i = bk * 4 + w;

  // alpha_i = leaky_relu((x_i.u)*(x_i.v))
  float su = 0.f, sv = 0.f;
#pragma unroll
  for (int kk = 0; kk < 4; ++kk) {
    int k = l + kk * 64;
    float xv = x[(size_t)i * INC + k];
    su = fmaf(xv, u[k], su);
    sv = fmaf(xv, v[k], sv);
  }
#pragma unroll
  for (int off = 32; off > 0; off >>= 1) {
    su += __shfl_xor(su, off);
    sv += __shfl_xor(sv, off);
  }
  float a = su * sv;
  float al = a > 0.f ? a : 0.2f * a;

  int d = deg[i];
  if (d > MAXD) d = MAXD;
  const int* crow = colbuf2 + (size_t)i * MAXD;
  if (l < d) scols[w][l] = crow[l];
  int l2 = l + 64;
  if (l2 < d) scols[w][l2] = crow[l2];
  __syncthreads();
  int c0s = -1, c1s = -2;
  if (l < d) c0s = scols[w][l];
  if (l2 < d) c1s = scols[w][l2];
  int m0 = 0, m1 = 0, f0 = 1, f1 = 1;
  for (int q = 0; q < d; ++q) {
    int cq = scols[w][q];
    if (cq == c0s) { m0++; if (q < l) f0 = 0; }
    if (cq == c1s) { m1++; if (q < l2) f1 = 0; }
  }
  int mm = m0 > m1 ? m0 : m1;
#pragma unroll
  for (int off = 32; off > 0; off >>= 1) {
    int b = __shfl_xor(mm, off);
    if (b > mm) mm = b;
  }
  float M = (al > 0.f) ? al * (float)mm : 0.f;
  float eMn = expf(-M);
  float se = 0.f;
  int nc = 0;
  float cf0 = 0.f, cf1 = 0.f;
  if (l < d && f0) {
    float e0 = expf(al * (float)m0 - M);
    se += e0; nc++; cf0 = e0 - eMn;
  }
  if (l2 < d && f1) {
    float e1 = expf(al * (float)m1 - M);
    se += e1; nc++; cf1 = e1 - eMn;
  }
#pragma unroll
  for (int off = 32; off > 0; off >>= 1) {
    se += __shfl_xor(se, off);
    nc += __shfl_xor(nc, off);
  }
  float Z = (float)(NN - nc) * eMn + se;
  float invZ = 1.0f / Z;
  if (l < d) scoef[w][l] = cf0 * invZ;
  if (l2 < d) scoef[w][l2] = cf1 * invZ;
  if (l == 0) rowscale[i] = eMn * invZ;

  // gather x rows: lane owns channels [4l, 4l+4); 2-way unrolled.
  int c0 = l * 4;
  float acc0 = 0.f, acc1 = 0.f, acc2 = 0.f, acc3 = 0.f;
  int k = 0;
  for (; k + 2 <= d; k += 2) {
    int ca = scols[w][k], cb = scols[w][k + 1];
    float fa = scoef[w][k], fb = scoef[w][k + 1];
    uint2 pa = *(const uint2*)(xb + (size_t)ca * INC + c0);
    uint2 pb = *(const uint2*)(xb + (size_t)cb * INC + c0);
    acc0 = fmaf(fa, blo(pa.x), fmaf(fb, blo(pb.x), acc0));
    acc1 = fmaf(fa, bhi(pa.x), fmaf(fb, bhi(pb.x), acc1));
    acc2 = fmaf(fa, blo(pa.y), fmaf(fb, blo(pb.y), acc2));
    acc3 = fmaf(fa, bhi(pa.y), fmaf(fb, bhi(pb.y), acc3));
  }
  if (k < d) {
    int ca = scols[w][k];
    float fa = scoef[w][k];
    uint2 pa = *(const uint2*)(xb + (size_t)ca * INC + c0);
    acc0 = fmaf(fa, blo(pa.x), acc0);
    acc1 = fmaf(fa, bhi(pa.x), acc1);
    acc2 = fmaf(fa, blo(pa.y), acc2);
    acc3 = fmaf(fa, bhi(pa.y), acc3);
  }
  ushort4 yo;
  yo.x = f2bu(acc0);
  yo.y = f2bu(acc1);
  yo.z = f2bu(acc2);
  yo.w = f2bu(acc3);
  *(ushort4*)(y + (size_t)i * INC + c0) = yo;
}

// out = elu( y @ Wcb^T + rowscale*gsum )  [8192,512] f32, written directly.
// MFMA 32x32x16, 64x64 tile, 2x2 waves; fused epilogue.
__global__ __launch_bounds__(256) void k_gemm4(const unsigned short* __restrict__ y,
                                               const unsigned short* __restrict__ wb,
                                               const float* __restrict__ rowscale,
                                               const float* __restrict__ gsum,
                                               float* __restrict__ out) {
  __shared__ float srs[64];
  int bk = blockIdx.x, t = threadIdx.x;
  int w = t >> 6, l = t & 63;
  int bx = bk & 7, by = bk >> 3;
  if (t < 64) srs[t] = rowscale[by * 64 + t];
  int wm = w >> 1, wn = w & 1;
  int r0 = by * 64 + wm * 32;
  int c0 = bx * 64 + wn * 32;
  int lr = l & 31;
  int lk = (l >> 5) * 8;
  const unsigned short* pa = y + (size_t)(r0 + lr) * INC + lk;
  const unsigned short* pb = wb + (size_t)(c0 + lr) * INC + lk;
  f32x16 acc = {};
#pragma unroll
  for (int k0 = 0; k0 < INC; k0 += 16) {
    bf16x8 a = *(const bf16x8*)(pa + k0);
    bf16x8 b = *(const bf16x8*)(pb + k0);
    acc = __builtin_amdgcn_mfma_f32_32x32x16_bf16(a, b, acc, 0, 0, 0);
  }
  __syncthreads();
  // C/D: col = lane&31, row = (reg&3) + 8*(reg>>2) + 4*(lane>>5)
  int col = c0 + lr;
  float gs = gsum[col];
  int lrb = wm * 32 + 4 * (l >> 5);
#pragma unroll
  for (int reg = 0; reg < 16; ++reg) {
    int lrow = lrb + (reg & 3) + 8 * (reg >> 2);
    float val = acc[reg] + srs[lrow] * gs;
    val = val > 0.f ? val : expm1f(val);
    out[(size_t)(by * 64 + lrow) * OUTC + col] = val;
  }
}

extern "C" void kernel_launch(void* const* d_in, const int* in_sizes, int n_in,
                              void* d_out, int out_size, void* d_ws, size_t ws_size,
                              hipStream_t stream) {
  const float* x = (const float*)d_in[0];
  const int* ei = (const int*)d_in[1];
  const float* W = (const float*)d_in[2];
  const float* att_w = (const float*)d_in[3];
  const float* lin_w = (const float*)d_in[4];
  float* out = (float*)d_out;
  const int* erow = ei;
  const int* ecol = ei + NE;

  char* ws = (char*)d_ws;
  size_t off = 0;
  auto alloc = [&](size_t bytes) {
    void* p = ws + off;
    off = (off + bytes + 255) & ~(size_t)255;
    return p;
  };
  float* u = (float*)alloc(INC * 4);
  float* v = (float*)alloc(INC * 4);
  float* xsum = (float*)alloc(INC * 4);
  float* xpartT = (float*)alloc(INC * 256 * 4);
  float* gsum = (float*)alloc(OUTC * 4);
  float* rowscale = (float*)alloc(NN * 4);
  float* part = (float*)alloc((size_t)JC * OUTC * INC * 4);
  float* uvpart = (float*)alloc(JC * 2 * INC * 4);
  unsigned short* Wcb = (unsigned short*)alloc((size_t)OUTC * INC * 2);
  unsigned short* xb = (unsigned short*)alloc((size_t)NN * INC * 2);
  unsigned short* y = (unsigned short*)alloc((size_t)NN * INC * 2);
  int* deg = (int*)alloc(NN * 4);
  int* colbuf2 = (int*)alloc((size_t)NN * MAXD * 4);
  (void)ws_size; (void)in_sizes; (void)n_in; (void)out_size;

  k_p0<<<256 + 1024, 256, 0, stream>>>(x, W, att_w, lin_w, xpartT, xb, deg, part, uvpart);
  k_p1<<<385, 256, 0, stream>>>(xpartT, xsum, erow, ecol, deg, colbuf2, part, uvpart, Wcb, u, v);
  k_sagg2<<<NN / 4 + 32, 256, 0, stream>>>(x, u, v, xb, deg, colbuf2, Wcb, xsum, y, rowscale, gsum);
  k_gemm4<<<1024, 256, 0, stream>>>(y, Wcb, rowscale, gsum, out);
}

// Round 16
// 70.904 us; speedup vs baseline: 1.5041x; 1.0030x over previous
//
#include <hip/hip_runtime.h>
#include <hip/hip_bf16.h>

#define NN 8192
#define INC 256
#define OUTC 512
#define NE 262144
#define MAXD 128
#define JC 8
#define JLEN 64  // OUTC / JC

typedef __hip_bfloat16 bf16;
typedef short bf16x8 __attribute__((ext_vector_type(8)));
typedef float f32x16 __attribute__((ext_vector_type(16)));

__device__ inline unsigned short f2bu(float f) {
  __hip_bfloat16 b = __float2bfloat16(f);
  return *reinterpret_cast<unsigned short*>(&b);
}
__device__ inline float blo(unsigned int x) { return __uint_as_float(x << 16); }
__device__ inline float bhi(unsigned int x) { return __uint_as_float(x & 0xffff0000u); }
__device__ inline float b2f(unsigned short s) { return __uint_as_float(((unsigned int)s) << 16); }

// P0: blocks 0..255 = x col-partials + bf16 cast + deg zero;
// blocks 256..1279 = Wc j-chunk partials (+ u,v partials on o-quad 0).
__global__ __launch_bounds__(256) void k_p0(const float* __restrict__ x,
                                            const float* __restrict__ W,
                                            const float* __restrict__ att_w,
                                            const float* __restrict__ lin_w,
                                            float* __restrict__ xpartT,
                                            unsigned short* __restrict__ xb,
                                            int* __restrict__ deg,
                                            float* __restrict__ part,
                                            float* __restrict__ uvpart) {
  int b = blockIdx.x, t = threadIdx.x;
  if (b < 256) {
    int gid = b * 256 + t;
    if (gid < NN) deg[gid] = 0;
    float acc = 0.f;
    int r0 = b * (NN / 256);
#pragma unroll 8
    for (int r = r0; r < r0 + NN / 256; ++r) {
      float xv = x[r * INC + t];
      acc += xv;
      xb[r * INC + t] = f2bu(xv);
    }
    xpartT[t * 256 + b] = acc;
    return;
  }
  int bid2 = b - 256;      // 0..1023
  int q = bid2 >> 3;       // o-quad 0..127
  int jc = bid2 & 7;
  int j0 = jc * JLEN;
  int o0 = q * 4;
  float a0 = 0.f, a1 = 0.f, a2 = 0.f, a3 = 0.f, su = 0.f, sv = 0.f;
  const float* lw0 = lin_w + (size_t)(o0 + 0) * OUTC + j0;
  const float* lw1 = lin_w + (size_t)(o0 + 1) * OUTC + j0;
  const float* lw2 = lin_w + (size_t)(o0 + 2) * OUTC + j0;
  const float* lw3 = lin_w + (size_t)(o0 + 3) * OUTC + j0;
#pragma unroll 8
  for (int jj = 0; jj < JLEN; ++jj) {
    float wv = W[(j0 + jj) * INC + t];
    a0 = fmaf(lw0[jj], wv, a0);
    a1 = fmaf(lw1[jj], wv, a1);
    a2 = fmaf(lw2[jj], wv, a2);
    a3 = fmaf(lw3[jj], wv, a3);
    if (q == 0) { su = fmaf(att_w[j0 + jj], wv, su); sv += wv; }
  }
  float* pb = part + ((size_t)jc * OUTC + o0) * INC + t;
  pb[0] = a0;
  pb[INC] = a1;
  pb[2 * INC] = a2;
  pb[3 * INC] = a3;
  if (q == 0) {
    uvpart[(jc * 2 + 0) * INC + t] = su;
    uvpart[(jc * 2 + 1) * INC + t] = sv;
  }
}

// P1 (385 blocks):
//  blocks 0..255: xsum reduce + 4 edges/thread atomicAdd(deg)->slot scatter
//  blocks 256..383: Wc reduce -> Wcb bf16
//  block 384: u,v
__global__ __launch_bounds__(256) void k_p1(const float* __restrict__ xpartT,
                                            float* __restrict__ xsum,
                                            const int* __restrict__ erow,
                                            const int* __restrict__ ecol,
                                            int* __restrict__ deg,
                                            int* __restrict__ colbuf2,
                                            const float* __restrict__ part,
                                            const float* __restrict__ uvpart,
                                            unsigned short* __restrict__ Wcb,
                                            float* __restrict__ u,
                                            float* __restrict__ v) {
  __shared__ float sred[4];
  int b = blockIdx.x, t = threadIdx.x;
  int l = t & 63, w = t >> 6;
  if (b < 256) {
    float r = xpartT[b * 256 + t];
#pragma unroll
    for (int off = 32; off > 0; off >>= 1) r += __shfl_xor(r, off);
    if (l == 0) sred[w] = r;
    int e0 = (b * 256 + t) * 4;
    int4 ev = *(const int4*)(erow + e0);
    int4 ec = *(const int4*)(ecol + e0);
    int s0 = atomicAdd(&deg[ev.x], 1);
    if (s0 < MAXD) colbuf2[ev.x * MAXD + s0] = ec.x;
    int s1 = atomicAdd(&deg[ev.y], 1);
    if (s1 < MAXD) colbuf2[ev.y * MAXD + s1] = ec.y;
    int s2 = atomicAdd(&deg[ev.z], 1);
    if (s2 < MAXD) colbuf2[ev.z * MAXD + s2] = ec.z;
    int s3 = atomicAdd(&deg[ev.w], 1);
    if (s3 < MAXD) colbuf2[ev.w * MAXD + s3] = ec.w;
    __syncthreads();
    if (t == 0) xsum[b] = sred[0] + sred[1] + sred[2] + sred[3];
  } else if (b < 384) {
    int o0 = (b - 256) * 4;
#pragma unroll
    for (int oo = 0; oo < 4; ++oo) {
      float s = 0.f;
#pragma unroll
      for (int jc = 0; jc < JC; ++jc)
        s += part[((size_t)jc * OUTC + o0 + oo) * INC + t];
      Wcb[(size_t)(o0 + oo) * INC + t] = f2bu(s);
    }
  } else {
    float su = 0.f, sv = 0.f;
#pragma unroll
    for (int jc = 0; jc < JC; ++jc) {
      su += uvpart[(jc * 2 + 0) * INC + t];
      sv += uvpart[(jc * 2 + 1) * INC + t];
    }
    u[t] = su;
    v[t] = sv;
  }
}

// Coeff + gather-x aggregation: one wave per row.
// y[i,:] = sum_k cf_k * xb[col_k, :]  (bf16 out), rowscale[i] = e^{-M}/Z.
// Blocks 2048..2079: gsum[o] = Wcb[o,:].xsum
__global__ __launch_bounds__(256) void k_sagg2(const float* __restrict__ x,
                                               const float* __restrict__ u,
                                               const float* __restrict__ v,
                                               const unsigned short* __restrict__ xb,
                                               const int* __restrict__ deg,
                                               const int* __restrict__ colbuf2,
                                               const unsigned short* __restrict__ Wcb,
                                               const float* __restrict__ xsum,
                                               unsigned short* __restrict__ y,
                                               float* __restrict__ rowscale,
                                               float* __restrict__ gsum) {
  int bk = blockIdx.x, t = threadIdx.x;
  int w = t >> 6, l = t & 63;
  if (bk >= 2048) {
    __shared__ float sredg[4];
    int o0 = (bk - 2048) * 16;
    float xk = xsum[t];
    for (int oo = 0; oo < 16; ++oo) {
      float r = b2f(Wcb[(size_t)(o0 + oo) * INC + t]) * xk;
#pragma unroll
      for (int off = 32; off > 0; off >>= 1) r += __shfl_xor(r, off);
      if (l == 0) sredg[w] = r;
      __syncthreads();
      if (t == 0) gsum[o0 + oo] = sredg[0] + sredg[1] + sredg[2] + sredg[3];
      __syncthreads();
    }
    return;
  }
  __shared__ int scols[4][MAXD];
  __shared__ float scoef[4][MAXD];
  int i = bk * 4 + w;

  // alpha_i = leaky_relu((x_i.u)*(x_i.v))
  float su = 0.f, sv = 0.f;
#pragma unroll
  for (int kk = 0; kk < 4; ++kk) {
    int k = l + kk * 64;
    float xv = x[(size_t)i * INC + k];
    su = fmaf(xv, u[k], su);
    sv = fmaf(xv, v[k], sv);
  }
#pragma unroll
  for (int off = 32; off > 0; off >>= 1) {
    su += __shfl_xor(su, off);
    sv += __shfl_xor(sv, off);
  }
  float a = su * sv;
  float al = a > 0.f ? a : 0.2f * a;

  int d = deg[i];
  if (d > MAXD) d = MAXD;
  const int* crow = colbuf2 + (size_t)i * MAXD;
  if (l < d) scols[w][l] = crow[l];
  int l2 = l + 64;
  if (l2 < d) scols[w][l2] = crow[l2];
  __syncthreads();
  int c0s = -1, c1s = -2;
  if (l < d) c0s = scols[w][l];
  if (l2 < d) c1s = scols[w][l2];
  int m0 = 0, m1 = 0, f0 = 1, f1 = 1;
  for (int q = 0; q < d; ++q) {
    int cq = scols[w][q];
    if (cq == c0s) { m0++; if (q < l) f0 = 0; }
    if (cq == c1s) { m1++; if (q < l2) f1 = 0; }
  }
  int mm = m0 > m1 ? m0 : m1;
#pragma unroll
  for (int off = 32; off > 0; off >>= 1) {
    int b = __shfl_xor(mm, off);
    if (b > mm) mm = b;
  }
  float M = (al > 0.f) ? al * (float)mm : 0.f;
  float eMn = expf(-M);
  float se = 0.f;
  int nc = 0;
  float cf0 = 0.f, cf1 = 0.f;
  if (l < d && f0) {
    float e0 = expf(al * (float)m0 - M);
    se += e0; nc++; cf0 = e0 - eMn;
  }
  if (l2 < d && f1) {
    float e1 = expf(al * (float)m1 - M);
    se += e1; nc++; cf1 = e1 - eMn;
  }
#pragma unroll
  for (int off = 32; off > 0; off >>= 1) {
    se += __shfl_xor(se, off);
    nc += __shfl_xor(nc, off);
  }
  float Z = (float)(NN - nc) * eMn + se;
  float invZ = 1.0f / Z;
  if (l < d) scoef[w][l] = cf0 * invZ;
  if (l2 < d) scoef[w][l2] = cf1 * invZ;
  if (l == 0) rowscale[i] = eMn * invZ;

  // gather x rows: lane owns channels [4l, 4l+4); 4-way unrolled (4 loads in flight).
  int c0 = l * 4;
  float acc0 = 0.f, acc1 = 0.f, acc2 = 0.f, acc3 = 0.f;
  int k = 0;
  for (; k + 4 <= d; k += 4) {
    int ca = scols[w][k], cb = scols[w][k + 1];
    int cc = scols[w][k + 2], cd = scols[w][k + 3];
    float fa = scoef[w][k], fb = scoef[w][k + 1];
    float fc = scoef[w][k + 2], fd = scoef[w][k + 3];
    uint2 pa = *(const uint2*)(xb + (size_t)ca * INC + c0);
    uint2 pb = *(const uint2*)(xb + (size_t)cb * INC + c0);
    uint2 pc = *(const uint2*)(xb + (size_t)cc * INC + c0);
    uint2 pd = *(const uint2*)(xb + (size_t)cd * INC + c0);
    acc0 = fmaf(fa, blo(pa.x), fmaf(fb, blo(pb.x), acc0));
    acc1 = fmaf(fa, bhi(pa.x), fmaf(fb, bhi(pb.x), acc1));
    acc2 = fmaf(fa, blo(pa.y), fmaf(fb, blo(pb.y), acc2));
    acc3 = fmaf(fa, bhi(pa.y), fmaf(fb, bhi(pb.y), acc3));
    acc0 = fmaf(fc, blo(pc.x), fmaf(fd, blo(pd.x), acc0));
    acc1 = fmaf(fc, bhi(pc.x), fmaf(fd, bhi(pd.x), acc1));
    acc2 = fmaf(fc, blo(pc.y), fmaf(fd, blo(pd.y), acc2));
    acc3 = fmaf(fc, bhi(pc.y), fmaf(fd, bhi(pd.y), acc3));
  }
  for (; k < d; ++k) {
    int ca = scols[w][k];
    float fa = scoef[w][k];
    uint2 pa = *(const uint2*)(xb + (size_t)ca * INC + c0);
    acc0 = fmaf(fa, blo(pa.x), acc0);
    acc1 = fmaf(fa, bhi(pa.x), acc1);
    acc2 = fmaf(fa, blo(pa.y), acc2);
    acc3 = fmaf(fa, bhi(pa.y), acc3);
  }
  ushort4 yo;
  yo.x = f2bu(acc0);
  yo.y = f2bu(acc1);
  yo.z = f2bu(acc2);
  yo.w = f2bu(acc3);
  *(ushort4*)(y + (size_t)i * INC + c0) = yo;
}

// out = elu( y @ Wcb^T + rowscale*gsum )  [8192,512] f32, written directly.
// MFMA 32x32x16, 64x64 tile, 2x2 waves; fused epilogue.
__global__ __launch_bounds__(256) void k_gemm4(const unsigned short* __restrict__ y,
                                               const unsigned short* __restrict__ wb,
                                               const float* __restrict__ rowscale,
                                               const float* __restrict__ gsum,
                                               float* __restrict__ out) {
  __shared__ float srs[64];
  int bk = blockIdx.x, t = threadIdx.x;
  int w = t >> 6, l = t & 63;
  int bx = bk & 7, by = bk >> 3;
  if (t < 64) srs[t] = rowscale[by * 64 + t];
  int wm = w >> 1, wn = w & 1;
  int r0 = by * 64 + wm * 32;
  int c0 = bx * 64 + wn * 32;
  int lr = l & 31;
  int lk = (l >> 5) * 8;
  const unsigned short* pa = y + (size_t)(r0 + lr) * INC + lk;
  const unsigned short* pb = wb + (size_t)(c0 + lr) * INC + lk;
  f32x16 acc = {};
#pragma unroll
  for (int k0 = 0; k0 < INC; k0 += 16) {
    bf16x8 a = *(const bf16x8*)(pa + k0);
    bf16x8 b = *(const bf16x8*)(pb + k0);
    acc = __builtin_amdgcn_mfma_f32_32x32x16_bf16(a, b, acc, 0, 0, 0);
  }
  __syncthreads();
  // C/D: col = lane&31, row = (reg&3) + 8*(reg>>2) + 4*(lane>>5)
  int col = c0 + lr;
  float gs = gsum[col];
  int lrb = wm * 32 + 4 * (l >> 5);
#pragma unroll
  for (int reg = 0; reg < 16; ++reg) {
    int lrow = lrb + (reg & 3) + 8 * (reg >> 2);
    float val = acc[reg] + srs[lrow] * gs;
    val = val > 0.f ? val : expm1f(val);
    out[(size_t)(by * 64 + lrow) * OUTC + col] = val;
  }
}

extern "C" void kernel_launch(void* const* d_in, const int* in_sizes, int n_in,
                              void* d_out, int out_size, void* d_ws, size_t ws_size,
                              hipStream_t stream) {
  const float* x = (const float*)d_in[0];
  const int* ei = (const int*)d_in[1];
  const float* W = (const float*)d_in[2];
  const float* att_w = (const float*)d_in[3];
  const float* lin_w = (const float*)d_in[4];
  float* out = (float*)d_out;
  const int* erow = ei;
  const int* ecol = ei + NE;

  char* ws = (char*)d_ws;
  size_t off = 0;
  auto alloc = [&](size_t bytes) {
    void* p = ws + off;
    off = (off + bytes + 255) & ~(size_t)255;
    return p;
  };
  float* u = (float*)alloc(INC * 4);
  float* v = (float*)alloc(INC * 4);
  float* xsum = (float*)alloc(INC * 4);
  float* xpartT = (float*)alloc(INC * 256 * 4);
  float* gsum = (float*)alloc(OUTC * 4);
  float* rowscale = (float*)alloc(NN * 4);
  float* part = (float*)alloc((size_t)JC * OUTC * INC * 4);
  float* uvpart = (float*)alloc(JC * 2 * INC * 4);
  unsigned short* Wcb = (unsigned short*)alloc((size_t)OUTC * INC * 2);
  unsigned short* xb = (unsigned short*)alloc((size_t)NN * INC * 2);
  unsigned short* y = (unsigned short*)alloc((size_t)NN * INC * 2);
  int* deg = (int*)alloc(NN * 4);
  int* colbuf2 = (int*)alloc((size_t)NN * MAXD * 4);
  (void)ws_size; (void)in_sizes; (void)n_in; (void)out_size;

  k_p0<<<256 + 1024, 256, 0, stream>>>(x, W, att_w, lin_w, xpartT, xb, deg, part, uvpart);
  k_p1<<<385, 256, 0, stream>>>(xpartT, xsum, erow, ecol, deg, colbuf2, part, uvpart, Wcb, u, v);
  k_sagg2<<<NN / 4 + 32, 256, 0, stream>>>(x, u, v, xb, deg, colbuf2, Wcb, xsum, y, rowscale, gsum);
  k_gemm4<<<1024, 256, 0, stream>>>(y, Wcb, rowscale, gsum, out);
}